// Round 1
// baseline (257.403 us; speedup 1.0000x reference)
//
#include <hip/hip_runtime.h>

// GCN layer: h = mean_{e: dst=v} feature[src(e)]  (or feature[v] if no in-edges)
//            out = relu(h @ W^T + b)
// Sizes: N=50000 nodes, F=64 feats, E=800000 edges, W is [64,64], b [64].

#define F 64

// --- Kernel 1: edge scatter. 64 lanes per edge, one atomicAdd per (edge,feat).
__global__ __launch_bounds__(256) void gcn_edge_scatter(
    const float* __restrict__ feature,
    const int* __restrict__ esrc,
    const int* __restrict__ edst,
    float* __restrict__ agg,   // [N,F], pre-zeroed (lives in d_out)
    float* __restrict__ cnt,   // [N],   pre-zeroed (lives in d_ws)
    int n_edges)
{
    int t = blockIdx.x * blockDim.x + threadIdx.x;
    int e = t >> 6;         // edge id
    int f = t & 63;         // feature id
    if (e >= n_edges) return;
    int s = esrc[e];
    int d = edst[e];
    atomicAdd(&agg[(long)d * F + f], feature[(long)s * F + f]);
    if (f == 0) atomicAdd(&cnt[d], 1.0f);
}

// --- Kernel 2: per-node mean/fallback + linear(64x64) + bias + ReLU, in place
// over the agg buffer (each block only touches its own 4 rows).
__global__ __launch_bounds__(256) void gcn_node_apply(
    const float* __restrict__ feature,
    const float* __restrict__ W,    // [64 out][64 in], row-major
    const float* __restrict__ bias, // [64]
    const float* __restrict__ cnt,  // [N]
    float* __restrict__ inout,      // agg in, result out  [N,F]
    int n_nodes)
{
    // W transposed in LDS, padded to stride 65 so lanes f=0..63 reading
    // sWt[k*65+f] are consecutive (conflict-free), and the transposed writes
    // (stride 65) are also conflict-free.
    __shared__ float sWt[64 * 65];
    __shared__ float sh[4][64];

    int tid = threadIdx.x;
    for (int i = tid; i < 64 * 64; i += 256) {
        int fo = i >> 6;   // out index (row of W)
        int k  = i & 63;   // in index
        sWt[k * 65 + fo] = W[i];
    }

    int g = tid >> 6;               // wave id == node group 0..3 (wave-uniform)
    int f = tid & 63;               // lane == feature index
    int n = blockIdx.x * 4 + g;

    float h = 0.0f;
    if (n < n_nodes) {
        float c = cnt[n];           // wave-uniform
        if (c > 0.0f) {
            h = inout[(long)n * F + f] / c;
        } else {
            h = feature[(long)n * F + f];
        }
    }
    sh[g][f] = h;
    __syncthreads();

    float acc = bias[f];
    #pragma unroll
    for (int k = 0; k < 64; ++k) {
        acc = fmaf(sh[g][k], sWt[k * 65 + f], acc);  // sh broadcast, sWt conflict-free
    }
    if (n < n_nodes) {
        inout[(long)n * F + f] = fmaxf(acc, 0.0f);
    }
}

extern "C" void kernel_launch(void* const* d_in, const int* in_sizes, int n_in,
                              void* d_out, int out_size, void* d_ws, size_t ws_size,
                              hipStream_t stream)
{
    const float* feature = (const float*)d_in[0];
    const int*   esrc    = (const int*)d_in[1];
    const int*   edst    = (const int*)d_in[2];
    const float* W       = (const float*)d_in[3];
    const float* bias    = (const float*)d_in[4];

    int n_nodes = in_sizes[0] / F;      // 50000
    int n_edges = in_sizes[1];          // 800000

    float* agg = (float*)d_out;         // [N,F] accumulator, becomes output
    float* cnt = (float*)d_ws;          // [N] in-degree counts

    // Zero accumulators (harness poisons with 0xAA and never re-poisons).
    hipMemsetAsync(agg, 0, (size_t)n_nodes * F * sizeof(float), stream);
    hipMemsetAsync(cnt, 0, (size_t)n_nodes * sizeof(float), stream);

    // Scatter: one thread per (edge, feature).
    {
        long total = (long)n_edges * F;
        int grid = (int)((total + 255) / 256);
        gcn_edge_scatter<<<grid, 256, 0, stream>>>(feature, esrc, edst, agg, cnt, n_edges);
    }

    // Node apply: 4 nodes per 256-thread block.
    {
        int grid = (n_nodes + 3) / 4;
        gcn_node_apply<<<grid, 256, 0, stream>>>(feature, W, bias, cnt, agg, n_nodes);
    }
}

// Round 4
// 182.286 us; speedup vs baseline: 1.4121x; 1.4121x over previous
//
#include <hip/hip_runtime.h>

// GCN layer: h = mean_{e: dst=v} feature[src(e)]  (or feature[v] if no in-edges)
//            out = relu(h @ W^T + b)
// N=50000 nodes, F=64 feats, E=800000 edges.
//
// Strategy: counting-sort edges by destination (deg -> scan -> bucket), then a
// fused per-node kernel gathers+means src features and applies the linear.
// This replaces 51.2M write-through f32 atomics (225MB HBM writes, round-1
// bottleneck) with 1.6M int atomics + cacheable reads.

#define F 64
#define SCAN_BLK 256
#define SCAN_ELEMS 1024   // elements scanned per block (4 per thread)

// ---------- counting sort ----------
__global__ __launch_bounds__(256) void k_deg(const int* __restrict__ edst,
                                             int* __restrict__ deg, int E) {
    int e = blockIdx.x * 256 + threadIdx.x;
    if (e < E) atomicAdd(&deg[edst[e]], 1);
}

__global__ __launch_bounds__(SCAN_BLK) void k_part(const int* __restrict__ deg,
                                                   int* __restrict__ part, int N) {
    int b = blockIdx.x, tid = threadIdx.x;
    int i0 = b * SCAN_ELEMS + tid * 4;
    int s = 0;
#pragma unroll
    for (int k = 0; k < 4; ++k) { int i = i0 + k; if (i < N) s += deg[i]; }
    // wave64 reduce, then cross-wave via LDS
    for (int d = 32; d; d >>= 1) s += __shfl_down(s, d);
    __shared__ int red[4];
    int w = tid >> 6;
    if ((tid & 63) == 0) red[w] = s;
    __syncthreads();
    if (tid == 0) part[b] = red[0] + red[1] + red[2] + red[3];
}

// single wave: exclusive scan of <=64 block partials
__global__ void k_root(int* __restrict__ part, int nb) {
    int lane = threadIdx.x;
    int v = (lane < nb) ? part[lane] : 0;
    int orig = v;
    for (int d = 1; d < 64; d <<= 1) {
        int t = __shfl_up(v, d);
        if (lane >= d) v += t;
    }
    if (lane < nb) part[lane] = v - orig;   // exclusive
}

__global__ __launch_bounds__(SCAN_BLK) void k_final(const int* __restrict__ deg,
                                                    const int* __restrict__ part,
                                                    int* __restrict__ off,
                                                    int* __restrict__ cursor,
                                                    int N, int E) {
    int b = blockIdx.x, tid = threadIdx.x;
    int i0 = b * SCAN_ELEMS + tid * 4;
    int v[4]; int s = 0;
#pragma unroll
    for (int k = 0; k < 4; ++k) { int i = i0 + k; v[k] = (i < N) ? deg[i] : 0; s += v[k]; }
    __shared__ int sc[SCAN_BLK];
    sc[tid] = s;
    __syncthreads();
    for (int d = 1; d < SCAN_BLK; d <<= 1) {
        int t = (tid >= d) ? sc[tid - d] : 0;
        __syncthreads();
        sc[tid] += t;
        __syncthreads();
    }
    int exc = sc[tid] - s;                  // exclusive prefix of thread sums
    int run = part[b] + exc;
#pragma unroll
    for (int k = 0; k < 4; ++k) {
        int i = i0 + k;
        if (i < N) { off[i] = run; cursor[i] = run; run += v[k]; }
    }
    if (b == 0 && tid == 0) off[N] = E;     // total = every edge has dst in [0,N)
}

__global__ __launch_bounds__(256) void k_bucket(const int* __restrict__ esrc,
                                                const int* __restrict__ edst,
                                                int* __restrict__ cursor,
                                                int* __restrict__ bucket, int E) {
    int e = blockIdx.x * 256 + threadIdx.x;
    if (e >= E) return;
    int d = edst[e];
    int p = atomicAdd(&cursor[d], 1);
    bucket[p] = esrc[e];
}

// ---------- fused gather-mean + linear ----------
__global__ __launch_bounds__(256) void k_node(const float* __restrict__ feature,
                                              const int* __restrict__ off,
                                              const int* __restrict__ bucket,
                                              const float* __restrict__ W,
                                              const float* __restrict__ bias,
                                              float* __restrict__ out, int N) {
    // W transposed in LDS, stride 65 -> conflict-free reads sWt[k*65+f]
    __shared__ float sWt[64 * 65];
    __shared__ float sh[4][64];
    int tid = threadIdx.x;
    for (int i = tid; i < 64 * 64; i += 256) {
        int fo = i >> 6, k = i & 63;
        sWt[k * 65 + fo] = W[i];
    }

    int w = tid >> 6;        // wave id = node slot
    int f = tid & 63;        // lane = feature
    int n = blockIdx.x * 4 + w;

    float h = 0.0f;
    if (n < N) {
        int beg = off[n], end = off[n + 1];
        float acc = 0.0f;
        for (int base = beg; base < end; base += 64) {
            int m = end - base; if (m > 64) m = 64;
            int myIdx = (f < m) ? bucket[base + f] : 0;   // coalesced index load
            for (int j = 0; j < m; ++j) {
                int s = __shfl(myIdx, j);                 // broadcast src id
                acc += feature[(long)s * F + f];          // coalesced 256B row read
            }
        }
        int c = end - beg;
        h = (c > 0) ? acc / (float)c : feature[(long)n * F + f];
    }
    sh[w][f] = h;
    __syncthreads();

    float accO = bias[f];
#pragma unroll
    for (int k = 0; k < 64; ++k)
        accO = fmaf(sh[w][k], sWt[k * 65 + f], accO);     // sh broadcast, sWt conflict-free
    if (n < N) out[(long)n * F + f] = fmaxf(accO, 0.0f);
}

// ---------- fallback (round-1 atomic path, used only if ws too small) ----------
__global__ __launch_bounds__(256) void gcn_edge_scatter(const float* __restrict__ feature,
                                                        const int* __restrict__ esrc,
                                                        const int* __restrict__ edst,
                                                        float* __restrict__ agg,
                                                        float* __restrict__ cnt, int E) {
    int t = blockIdx.x * blockDim.x + threadIdx.x;
    int e = t >> 6, f = t & 63;
    if (e >= E) return;
    atomicAdd(&agg[(long)edst[e] * F + f], feature[(long)esrc[e] * F + f]);
    if (f == 0) atomicAdd(&cnt[edst[e]], 1.0f);
}

__global__ __launch_bounds__(256) void gcn_node_apply(const float* __restrict__ feature,
                                                      const float* __restrict__ W,
                                                      const float* __restrict__ bias,
                                                      const float* __restrict__ cnt,
                                                      float* __restrict__ inout, int N) {
    __shared__ float sWt[64 * 65];
    __shared__ float sh[4][64];
    int tid = threadIdx.x;
    for (int i = tid; i < 64 * 64; i += 256) {
        int fo = i >> 6, k = i & 63;
        sWt[k * 65 + fo] = W[i];
    }
    int w = tid >> 6, f = tid & 63;
    int n = blockIdx.x * 4 + w;
    float h = 0.0f;
    if (n < N) {
        float c = cnt[n];
        h = (c > 0.0f) ? inout[(long)n * F + f] / c : feature[(long)n * F + f];
    }
    sh[w][f] = h;
    __syncthreads();
    float acc = bias[f];
#pragma unroll
    for (int k = 0; k < 64; ++k) acc = fmaf(sh[w][k], sWt[k * 65 + f], acc);
    if (n < N) inout[(long)n * F + f] = fmaxf(acc, 0.0f);
}

extern "C" void kernel_launch(void* const* d_in, const int* in_sizes, int n_in,
                              void* d_out, int out_size, void* d_ws, size_t ws_size,
                              hipStream_t stream) {
    const float* feature = (const float*)d_in[0];
    const int*   esrc    = (const int*)d_in[1];
    const int*   edst    = (const int*)d_in[2];
    const float* W       = (const float*)d_in[3];
    const float* bias    = (const float*)d_in[4];

    int N = in_sizes[0] / F;   // 50000
    int E = in_sizes[1];       // 800000

    // workspace layout (256B-aligned chunks)
    auto align256 = [](size_t x) { return (x + 255) & ~(size_t)255; };
    size_t sz_off    = align256((size_t)(N + 1) * sizeof(int));
    size_t sz_deg    = align256((size_t)N * sizeof(int));
    size_t sz_cursor = align256((size_t)N * sizeof(int));
    size_t sz_part   = align256(64 * sizeof(int));
    size_t sz_bucket = align256((size_t)E * sizeof(int));
    size_t need = sz_off + sz_deg + sz_cursor + sz_part + sz_bucket;

    int nb_scan = (N + SCAN_ELEMS - 1) / SCAN_ELEMS;  // 49, must be <= 64

    if (ws_size >= need && nb_scan <= 64) {
        char* ws = (char*)d_ws;
        int* off    = (int*)ws;                                   ws += sz_off;
        int* deg    = (int*)ws;                                   ws += sz_deg;
        int* cursor = (int*)ws;                                   ws += sz_cursor;
        int* part   = (int*)ws;                                   ws += sz_part;
        int* bucket = (int*)ws;

        hipMemsetAsync(deg, 0, (size_t)N * sizeof(int), stream);

        int gE = (E + 255) / 256;
        k_deg<<<gE, 256, 0, stream>>>(edst, deg, E);
        k_part<<<nb_scan, SCAN_BLK, 0, stream>>>(deg, part, N);
        k_root<<<1, 64, 0, stream>>>(part, nb_scan);
        k_final<<<nb_scan, SCAN_BLK, 0, stream>>>(deg, part, off, cursor, N, E);
        k_bucket<<<gE, 256, 0, stream>>>(esrc, edst, cursor, bucket, E);
        k_node<<<(N + 3) / 4, 256, 0, stream>>>(feature, off, bucket, W, bias,
                                                (float*)d_out, N);
    } else {
        // fallback: atomic scatter path
        float* agg = (float*)d_out;
        float* cnt = (float*)d_ws;
        hipMemsetAsync(agg, 0, (size_t)N * F * sizeof(float), stream);
        hipMemsetAsync(cnt, 0, (size_t)N * sizeof(float), stream);
        long total = (long)E * F;
        gcn_edge_scatter<<<(int)((total + 255) / 256), 256, 0, stream>>>(
            feature, esrc, edst, agg, cnt, E);
        gcn_node_apply<<<(N + 3) / 4, 256, 0, stream>>>(feature, W, bias, cnt, agg, N);
    }
}

// Round 5
// 152.303 us; speedup vs baseline: 1.6901x; 1.1969x over previous
//
#include <hip/hip_runtime.h>

// GCN layer: h = mean_{e: dst=v} feature[src(e)]  (or feature[v] if no in-edges)
//            out = relu(h @ W^T + b)
// N=50000 nodes, F=64 feats, E=800000 edges.
//
// Pipeline: counting-sort edges by dst (deg -> scan -> bucket), then fused
// gather-mean + linear. Round-5 change: k_node gathers 4 edges per
// global_load_dwordx4 (16 lanes x float4 each) with x2 unroll -> 8 edges in
// flight per wave, no shfl in the inner loop (was: 1 serial 4B load + shfl
// per edge -> latency-bound at 81us).

#define F 64
#define SCAN_BLK 256
#define SCAN_ELEMS 1024   // elements scanned per block (4 per thread)

// ---------- counting sort ----------
__global__ __launch_bounds__(256) void k_deg(const int* __restrict__ edst,
                                             int* __restrict__ deg, int E) {
    int e = blockIdx.x * 256 + threadIdx.x;
    if (e < E) atomicAdd(&deg[edst[e]], 1);
}

__global__ __launch_bounds__(SCAN_BLK) void k_part(const int* __restrict__ deg,
                                                   int* __restrict__ part, int N) {
    int b = blockIdx.x, tid = threadIdx.x;
    int i0 = b * SCAN_ELEMS + tid * 4;
    int s = 0;
#pragma unroll
    for (int k = 0; k < 4; ++k) { int i = i0 + k; if (i < N) s += deg[i]; }
    for (int d = 32; d; d >>= 1) s += __shfl_down(s, d);
    __shared__ int red[4];
    int w = tid >> 6;
    if ((tid & 63) == 0) red[w] = s;
    __syncthreads();
    if (tid == 0) part[b] = red[0] + red[1] + red[2] + red[3];
}

// single wave: exclusive scan of <=64 block partials
__global__ void k_root(int* __restrict__ part, int nb) {
    int lane = threadIdx.x;
    int v = (lane < nb) ? part[lane] : 0;
    int orig = v;
    for (int d = 1; d < 64; d <<= 1) {
        int t = __shfl_up(v, d);
        if (lane >= d) v += t;
    }
    if (lane < nb) part[lane] = v - orig;   // exclusive
}

__global__ __launch_bounds__(SCAN_BLK) void k_final(const int* __restrict__ deg,
                                                    const int* __restrict__ part,
                                                    int* __restrict__ off,
                                                    int* __restrict__ cursor,
                                                    int N, int E) {
    int b = blockIdx.x, tid = threadIdx.x;
    int i0 = b * SCAN_ELEMS + tid * 4;
    int v[4]; int s = 0;
#pragma unroll
    for (int k = 0; k < 4; ++k) { int i = i0 + k; v[k] = (i < N) ? deg[i] : 0; s += v[k]; }
    __shared__ int sc[SCAN_BLK];
    sc[tid] = s;
    __syncthreads();
    for (int d = 1; d < SCAN_BLK; d <<= 1) {
        int t = (tid >= d) ? sc[tid - d] : 0;
        __syncthreads();
        sc[tid] += t;
        __syncthreads();
    }
    int exc = sc[tid] - s;
    int run = part[b] + exc;
#pragma unroll
    for (int k = 0; k < 4; ++k) {
        int i = i0 + k;
        if (i < N) { off[i] = run; cursor[i] = run; run += v[k]; }
    }
    if (b == 0 && tid == 0) off[N] = E;
}

__global__ __launch_bounds__(256) void k_bucket(const int* __restrict__ esrc,
                                                const int* __restrict__ edst,
                                                int* __restrict__ cursor,
                                                int* __restrict__ bucket, int E) {
    int e = blockIdx.x * 256 + threadIdx.x;
    if (e >= E) return;
    int d = edst[e];
    int p = atomicAdd(&cursor[d], 1);
    bucket[p] = esrc[e];
}

// ---------- fused gather-mean + linear ----------
// wave layout: g = lane>>4 picks one of 4 edges per load step, c = lane&15
// picks the float4 column -> one global_load_dwordx4 fetches 4 full rows.
__global__ __launch_bounds__(256) void k_node(const float* __restrict__ feature,
                                              const int* __restrict__ off,
                                              const int* __restrict__ bucket,
                                              const float* __restrict__ W,
                                              const float* __restrict__ bias,
                                              float* __restrict__ out, int N) {
    __shared__ float sWt[64 * 65];   // W transposed, pad 65 -> conflict-free
    __shared__ float sh[4][64];
    int tid = threadIdx.x;
    for (int i = tid; i < 64 * 64; i += 256) {
        int fo = i >> 6, k = i & 63;
        sWt[k * 65 + fo] = W[i];
    }

    int w    = tid >> 6;     // wave id = node slot
    int lane = tid & 63;
    int g    = lane >> 4;    // edge sub-slot 0..3
    int c    = lane & 15;    // float4 column 0..15
    int n    = blockIdx.x * 4 + w;

    const float4* F4 = (const float4*)feature;

    if (n < N) {
        int beg = off[n], end = off[n + 1];
        int d = end - beg;
        float ax = 0.f, ay = 0.f, az = 0.f, aw = 0.f;
        float bx = 0.f, by = 0.f, bz = 0.f, bw = 0.f;
        for (int base = beg; base < end; base += 8) {
            int i0 = base + g, i1 = base + 4 + g;
            int s0 = (i0 < end) ? bucket[i0] : 0;    // predicated, stays in-array
            int s1 = (i1 < end) ? bucket[i1] : 0;
            float4 v0 = F4[(long)s0 * 16 + c];       // 256B row, coalesced per 16 lanes
            float4 v1 = F4[(long)s1 * 16 + c];
            if (i0 < end) { ax += v0.x; ay += v0.y; az += v0.z; aw += v0.w; }
            if (i1 < end) { bx += v1.x; by += v1.y; bz += v1.z; bw += v1.w; }
        }
        ax += bx; ay += by; az += bz; aw += bw;
        // reduce the 4 edge-groups (lanes differing in bits 4,5)
        ax += __shfl_xor(ax, 16); ax += __shfl_xor(ax, 32);
        ay += __shfl_xor(ay, 16); ay += __shfl_xor(ay, 32);
        az += __shfl_xor(az, 16); az += __shfl_xor(az, 32);
        aw += __shfl_xor(aw, 16); aw += __shfl_xor(aw, 32);
        int fw = c * 4 + g;                          // this lane's output feature
        float hv;
        if (d > 0) {
            float sel = (g == 0) ? ax : (g == 1) ? ay : (g == 2) ? az : aw;
            hv = sel * (1.0f / (float)d);
        } else {
            hv = feature[(long)n * F + fw];          // isolated node keeps h
        }
        sh[w][fw] = hv;
    }
    __syncthreads();

    float acc = bias[lane];
#pragma unroll
    for (int k = 0; k < 64; ++k)
        acc = fmaf(sh[w][k], sWt[k * 65 + lane], acc);   // sh broadcast, sWt conflict-free
    if (n < N) out[(long)n * F + lane] = fmaxf(acc, 0.0f);
}

extern "C" void kernel_launch(void* const* d_in, const int* in_sizes, int n_in,
                              void* d_out, int out_size, void* d_ws, size_t ws_size,
                              hipStream_t stream) {
    const float* feature = (const float*)d_in[0];
    const int*   esrc    = (const int*)d_in[1];
    const int*   edst    = (const int*)d_in[2];
    const float* W       = (const float*)d_in[3];
    const float* bias    = (const float*)d_in[4];

    int N = in_sizes[0] / F;   // 50000
    int E = in_sizes[1];       // 800000

    auto align256 = [](size_t x) { return (x + 255) & ~(size_t)255; };
    size_t sz_off    = align256((size_t)(N + 1) * sizeof(int));
    size_t sz_deg    = align256((size_t)N * sizeof(int));
    size_t sz_cursor = align256((size_t)N * sizeof(int));
    size_t sz_part   = align256(64 * sizeof(int));
    size_t sz_bucket = align256((size_t)E * sizeof(int));
    size_t need = sz_off + sz_deg + sz_cursor + sz_part + sz_bucket;

    int nb_scan = (N + SCAN_ELEMS - 1) / SCAN_ELEMS;  // 49, must be <= 64

    char* ws = (char*)d_ws;
    int* off    = (int*)ws;                                   ws += sz_off;
    int* deg    = (int*)ws;                                   ws += sz_deg;
    int* cursor = (int*)ws;                                   ws += sz_cursor;
    int* part   = (int*)ws;                                   ws += sz_part;
    int* bucket = (int*)ws;
    (void)need; (void)ws_size;  // need ~3.8MB; harness ws is larger

    hipMemsetAsync(deg, 0, (size_t)N * sizeof(int), stream);

    int gE = (E + 255) / 256;
    k_deg<<<gE, 256, 0, stream>>>(edst, deg, E);
    k_part<<<nb_scan, SCAN_BLK, 0, stream>>>(deg, part, N);
    k_root<<<1, 64, 0, stream>>>(part, nb_scan);
    k_final<<<nb_scan, SCAN_BLK, 0, stream>>>(deg, part, off, cursor, N, E);
    k_bucket<<<gE, 256, 0, stream>>>(esrc, edst, cursor, bucket, E);
    k_node<<<(N + 3) / 4, 256, 0, stream>>>(feature, off, bucket, W, bias,
                                            (float*)d_out, N);
}